// Round 3
// baseline (493.730 us; speedup 1.0000x reference)
//
#include <hip/hip_runtime.h>
#include <stdint.h>

#define NN 8192
#define FEAT 16

// conv_feats[i] = sigmoid(x[i,:] . w + b)   (fp32 in, fp32 out to ws)
__global__ void conv_kernel(const float* __restrict__ x,
                            const float* __restrict__ w,
                            const float* __restrict__ b,
                            float* __restrict__ out) {
    int i = blockIdx.x * blockDim.x + threadIdx.x;
    if (i >= NN) return;
    const float4* xr = (const float4*)(x + (size_t)i * FEAT);
    const float4* wr = (const float4*)w;
    float acc = b[0];
#pragma unroll
    for (int k = 0; k < 4; ++k) {
        float4 a = xr[k], ww = wr[k];
        acc += a.x * ww.x + a.y * ww.y + a.z * ww.z + a.w * ww.w;
    }
    out[i] = 1.f / (1.f + __expf(-acc));
}

// y[row] = act( W[row,:] . x + bias[row] )
// W: (NN, NN) fp32 row-major (torch (out,in)); x fp32; one row per 256-thread block.
template <bool TANH>
__global__ __launch_bounds__(256)
void matvec_kernel(const float* __restrict__ W,
                   const float* __restrict__ x,
                   const float* __restrict__ bias,
                   float* __restrict__ y) {
    const int row = blockIdx.x;
    const int t = threadIdx.x;
    const float* wr = W + (size_t)row * NN;

    float acc = 0.f;
#pragma unroll
    for (int it = 0; it < 8; ++it) {
        const int base = (it * 256 + t) * 4;           // 4 floats / thread / iter
        float4 wv = *(const float4*)(wr + base);
        float4 xv = *(const float4*)(x + base);
        acc += wv.x * xv.x + wv.y * xv.y + wv.z * xv.z + wv.w * xv.w;
    }

    // wave(64) shuffle reduce
#pragma unroll
    for (int off = 32; off > 0; off >>= 1)
        acc += __shfl_down(acc, off, 64);

    __shared__ float part[4];
    const int wave = t >> 6;
    const int lane = t & 63;
    if (lane == 0) part[wave] = acc;
    __syncthreads();

    if (t == 0) {
        float r = part[0] + part[1] + part[2] + part[3] + bias[row];
        if (TANH) r = tanhf(r);
        y[row] = r;
    }
}

extern "C" void kernel_launch(void* const* d_in, const int* in_sizes, int n_in,
                              void* d_out, int out_size, void* d_ws, size_t ws_size,
                              hipStream_t stream) {
    const float* x      = (const float*)d_in[0]; // (8192,16)
    const float* conv_w = (const float*)d_in[1]; // (16,)
    const float* conv_b = (const float*)d_in[2]; // (1,)
    const float* W1     = (const float*)d_in[3]; // (8192,8192)
    const float* b1     = (const float*)d_in[4]; // (8192,)
    const float* W2     = (const float*)d_in[5]; // (8192,8192)
    const float* b2     = (const float*)d_in[6]; // (8192,)
    float* out = (float*)d_out;                  // (8192,) fp32

    float* conv_feats = (float*)d_ws;            // 8192 floats
    float* h          = conv_feats + NN;         // 8192 floats

    conv_kernel<<<NN / 256, 256, 0, stream>>>(x, conv_w, conv_b, conv_feats);
    matvec_kernel<true ><<<NN, 256, 0, stream>>>(W1, conv_feats, b1, h);
    matvec_kernel<false><<<NN, 256, 0, stream>>>(W2, h, b2, out);
}